// Round 1
// 503.470 us; speedup vs baseline: 1.1502x; 1.1502x over previous
//
#include <hip/hip_runtime.h>
#include <math.h>

#define VOCN 50257
#define OUTD 512
#define HIDD 64
#define CURD 16
#define BB   32
#define SS   4096
#define NCH  256      // SS / CURD
#define KDIM 80       // HIDD + CURD
#define LNEPS 1e-5f

// ---------------------------------------------------------------------------
// helpers: DPP row16 reduce (VALU-only, replaces ds_bpermute shuffles)
// ---------------------------------------------------------------------------
#define DPP_ADD(x, ctrl) \
    ((x) + __int_as_float(__builtin_amdgcn_update_dpp( \
        0, __float_as_int(x), (ctrl), 0xf, 0xf, true)))

__device__ __forceinline__ float row16_sum(float x) {
    x = DPP_ADD(x, 0xB1);   // quad_perm [1,0,3,2]  (xor 1)
    x = DPP_ADD(x, 0x4E);   // quad_perm [2,3,0,1]  (xor 2)
    x = DPP_ADD(x, 0x141);  // row_half_mirror      (xor 4)
    x = DPP_ADD(x, 0x140);  // row_mirror           (xor 8)
    return x;               // every lane: sum of its 16-lane row
}

__device__ __forceinline__ float wave64_sum(float x) {
    float r = row16_sum(x);
    float a = __int_as_float(__builtin_amdgcn_readlane(__float_as_int(r), 0));
    float b = __int_as_float(__builtin_amdgcn_readlane(__float_as_int(r), 16));
    float c = __int_as_float(__builtin_amdgcn_readlane(__float_as_int(r), 32));
    float d = __int_as_float(__builtin_amdgcn_readlane(__float_as_int(r), 48));
    return (a + b) + (c + d);   // uniform (SGPR) value
}

// bf16 split helpers (round-to-nearest-even)
__device__ __forceinline__ unsigned short f2bf(float x) {
    unsigned u = __float_as_uint(x);
    u += 0x7fffu + ((u >> 16) & 1u);
    return (unsigned short)(u >> 16);
}
__device__ __forceinline__ float bf2f(unsigned short h) {
    return __uint_as_float(((unsigned)h) << 16);
}

typedef __attribute__((ext_vector_type(8))) short bf16x8;
typedef __attribute__((ext_vector_type(4))) float f32x4;

// ---------------------------------------------------------------------------
// Kernel 0: pack Wd (fp32 [80][512]) into MFMA B-fragment order, bf16 hi/lo,
// K zero-padded to 96. Layout: [s=k/32][col][g=(k%32)/8][e=k%8] contiguous 8.
// ---------------------------------------------------------------------------
__global__ __launch_bounds__(256) void wd_pack_kernel(
    const float* __restrict__ Wd,
    unsigned short* __restrict__ hi, unsigned short* __restrict__ lo)
{
    int idx = blockIdx.x * 256 + threadIdx.x;   // over 96*512
    if (idx >= 96 * 512) return;
    int k = idx / 512, c = idx % 512;
    float v = (k < KDIM) ? Wd[(size_t)k * OUTD + c] : 0.f;
    unsigned short h = f2bf(v);
    unsigned short l = f2bf(v - bf2f(h));
    int s = k >> 5, kk = k & 31, g = kk >> 3, e = kk & 7;
    size_t o = (((size_t)(s * 512 + c)) * 4 + g) * 8 + e;
    hi[o] = h;
    lo[o] = l;
}

// ---------------------------------------------------------------------------
// Kernel 1: attention, ONE WAVE per (t,b) tile, no barriers. (unchanged)
// ---------------------------------------------------------------------------
__global__ __launch_bounds__(256) void attn_kernel(
    const int* __restrict__ x, const float* __restrict__ emb,
    const float* __restrict__ Wq, const float* __restrict__ bq,
    const float* __restrict__ Wk, const float* __restrict__ bk,
    const float* __restrict__ Wv, const float* __restrict__ bv,
    const float* __restrict__ g_lim, const float* __restrict__ b_lim,
    float* __restrict__ combined)
{
    const int wid  = threadIdx.x >> 6;
    const int lane = threadIdx.x & 63;
    const int tile = blockIdx.x * 4 + wid;
    const int t = tile >> 5, b = tile & 31;
    const int i  = lane >> 2;
    const int jg = lane & 3;
    const int j0 = jg * 4;

    __shared__ __align__(16) float ldsT[4][4][16][20];
    float (*R)[20] = ldsT[wid][0];
    float (*Q)[20] = ldsT[wid][1];
    float (*K)[20] = ldsT[wid][2];
    float (*V)[20] = ldsT[wid][3];

    int myid = 0;
    if (lane < 16) myid = x[b * SS + t * CURD + lane];
    const int id_i = __shfl(myid, i, 64);

    float4 r4 = *(const float4*)(emb + (size_t)id_i * CURD + j0);
    *(float4*)&R[i][j0] = r4;

    float rrow[16];
    {
        float4 t0 = *(const float4*)&R[i][0];
        float4 t1 = *(const float4*)&R[i][4];
        float4 t2 = *(const float4*)&R[i][8];
        float4 t3 = *(const float4*)&R[i][12];
        rrow[0]=t0.x; rrow[1]=t0.y; rrow[2]=t0.z;  rrow[3]=t0.w;
        rrow[4]=t1.x; rrow[5]=t1.y; rrow[6]=t1.z;  rrow[7]=t1.w;
        rrow[8]=t2.x; rrow[9]=t2.y; rrow[10]=t2.z; rrow[11]=t2.w;
        rrow[12]=t3.x; rrow[13]=t3.y; rrow[14]=t3.z; rrow[15]=t3.w;
    }

    float4 q4 = *(const float4*)(bq + j0);
    float4 k4 = *(const float4*)(bk + j0);
    float4 v4 = *(const float4*)(bv + j0);
    #pragma unroll
    for (int k = 0; k < 16; ++k) {
        float rv = rrow[k];
        float4 wq4 = *(const float4*)(Wq + k * CURD + j0);
        float4 wk4 = *(const float4*)(Wk + k * CURD + j0);
        float4 wv4 = *(const float4*)(Wv + k * CURD + j0);
        q4.x = fmaf(rv, wq4.x, q4.x); q4.y = fmaf(rv, wq4.y, q4.y);
        q4.z = fmaf(rv, wq4.z, q4.z); q4.w = fmaf(rv, wq4.w, q4.w);
        k4.x = fmaf(rv, wk4.x, k4.x); k4.y = fmaf(rv, wk4.y, k4.y);
        k4.z = fmaf(rv, wk4.z, k4.z); k4.w = fmaf(rv, wk4.w, k4.w);
        v4.x = fmaf(rv, wv4.x, v4.x); v4.y = fmaf(rv, wv4.y, v4.y);
        v4.z = fmaf(rv, wv4.z, v4.z); v4.w = fmaf(rv, wv4.w, v4.w);
    }
    *(float4*)&Q[i][j0] = q4;
    *(float4*)&K[i][j0] = k4;
    *(float4*)&V[i][j0] = v4;

    float qrow[16];
    {
        float4 t0 = *(const float4*)&Q[i][0];
        float4 t1 = *(const float4*)&Q[i][4];
        float4 t2 = *(const float4*)&Q[i][8];
        float4 t3 = *(const float4*)&Q[i][12];
        qrow[0]=t0.x; qrow[1]=t0.y; qrow[2]=t0.z;  qrow[3]=t0.w;
        qrow[4]=t1.x; qrow[5]=t1.y; qrow[6]=t1.z;  qrow[7]=t1.w;
        qrow[8]=t2.x; qrow[9]=t2.y; qrow[10]=t2.z; qrow[11]=t2.w;
        qrow[12]=t3.x; qrow[13]=t3.y; qrow[14]=t3.z; qrow[15]=t3.w;
    }
    float sc[4];
    #pragma unroll
    for (int jj = 0; jj < 4; ++jj) {
        const int row = j0 + jj;
        float4 c0 = *(const float4*)&K[row][0];
        float4 c1 = *(const float4*)&K[row][4];
        float4 c2 = *(const float4*)&K[row][8];
        float4 c3 = *(const float4*)&K[row][12];
        float d0 = qrow[0]*c0.x + qrow[1]*c0.y + qrow[2]*c0.z + qrow[3]*c0.w;
        float d1 = qrow[4]*c1.x + qrow[5]*c1.y + qrow[6]*c1.z + qrow[7]*c1.w;
        float d2 = qrow[8]*c2.x + qrow[9]*c2.y + qrow[10]*c2.z + qrow[11]*c2.w;
        float d3 = qrow[12]*c3.x + qrow[13]*c3.y + qrow[14]*c3.z + qrow[15]*c3.w;
        sc[jj] = ((d0 + d1) + (d2 + d3)) * 0.25f;
    }

    float mx = fmaxf(fmaxf(sc[0], sc[1]), fmaxf(sc[2], sc[3]));
    mx = fmaxf(mx, __shfl_xor(mx, 1));
    mx = fmaxf(mx, __shfl_xor(mx, 2));
    float e0 = expf(sc[0]-mx), e1 = expf(sc[1]-mx),
          e2 = expf(sc[2]-mx), e3 = expf(sc[3]-mx);
    float es = (e0 + e1) + (e2 + e3);
    es += __shfl_xor(es, 1);
    es += __shfl_xor(es, 2);
    float rs = 1.f / es;
    float4 p4 = make_float4(e0*rs, e1*rs, e2*rs, e3*rs);
    *(float4*)&R[i][j0] = p4;

    float prow[16];
    {
        float4 t0 = *(const float4*)&R[i][0];
        float4 t1 = *(const float4*)&R[i][4];
        float4 t2 = *(const float4*)&R[i][8];
        float4 t3 = *(const float4*)&R[i][12];
        prow[0]=t0.x; prow[1]=t0.y; prow[2]=t0.z;  prow[3]=t0.w;
        prow[4]=t1.x; prow[5]=t1.y; prow[6]=t1.z;  prow[7]=t1.w;
        prow[8]=t2.x; prow[9]=t2.y; prow[10]=t2.z; prow[11]=t2.w;
        prow[12]=t3.x; prow[13]=t3.y; prow[14]=t3.z; prow[15]=t3.w;
    }
    float4 w4 = make_float4(0.f, 0.f, 0.f, 0.f);
    #pragma unroll
    for (int k = 0; k < 16; ++k) {
        float4 vk = *(const float4*)&V[k][j0];
        float pv = prow[k];
        w4.x = fmaf(pv, vk.x, w4.x); w4.y = fmaf(pv, vk.y, w4.y);
        w4.z = fmaf(pv, vk.z, w4.z); w4.w = fmaf(pv, vk.w, w4.w);
    }

    float s1 = (w4.x + w4.y) + (w4.z + w4.w);
    float s2 = (w4.x*w4.x + w4.y*w4.y) + (w4.z*w4.z + w4.w*w4.w);
    s1 += __shfl_xor(s1, 1); s1 += __shfl_xor(s1, 2);
    s2 += __shfl_xor(s2, 1); s2 += __shfl_xor(s2, 2);
    float m   = s1 * (1.f / 16.f);
    float var = s2 * (1.f / 16.f) - m * m;
    float inv = rsqrtf(var + LNEPS);
    float4 gl = *(const float4*)(g_lim + j0);
    float4 bl = *(const float4*)(b_lim + j0);
    float4 o;
    o.x = (w4.x - m) * inv * gl.x + bl.x;
    o.y = (w4.y - m) * inv * gl.y + bl.y;
    o.z = (w4.z - m) * inv * gl.z + bl.z;
    o.w = (w4.w - m) * inv * gl.w + bl.w;
    *(float4*)(combined + ((size_t)tile * CURD + i) * KDIM + j0) = o;
}

// ---------------------------------------------------------------------------
// Kernel 2: 512 chains, one wave each. v2:
//  - (m, var) reduce via DPP row16 + readlane (VALU, off the critical path)
//    instead of 12 serial ds_bpermute shuffles,
//  - watch row loaded by ALL lanes as 4 broadcast float4s, prefetched 2
//    iterations ahead (covers ~900cy HBM latency; no s_watch LDS round-trip).
// ---------------------------------------------------------------------------
__global__ __launch_bounds__(64) void rec_kernel(
    const float* __restrict__ Ws, const float* __restrict__ bs,
    const float* __restrict__ g_doubt, const float* __restrict__ b_doubt,
    float* __restrict__ combined)
{
    const int chain = blockIdx.x;       // b*16 + r
    const int b = chain >> 4;
    const int r = chain & 15;
    const int c = threadIdx.x;          // 0..63

    __shared__ __align__(16) float s_G[64];

    float Wsw[16];
    #pragma unroll
    for (int j = 0; j < 16; ++j) Wsw[j] = Ws[j * HIDD + c];

    float Wsp[64];
    float u = 0.f, w0 = 0.f;
    #pragma unroll
    for (int j = 0; j < 64; ++j) {
        float w   = Ws[(16 + j) * HIDD + c];
        float gdj = g_doubt[j];
        float bdj = b_doubt[j];
        Wsp[j] = gdj * w;
        u += Wsp[j];
        w0 = fmaf(bdj, w, w0);
    }
    const float bsc  = bs[c];
    const float gd_c = g_doubt[c];
    const float bd_c = b_doubt[c];

    size_t rowoff = ((size_t)b * CURD + r) * KDIM;          // t = 0
    const size_t stride = (size_t)BB * CURD * KDIM;

    // watch double-prefetch (broadcast loads: all lanes same address)
    float4 wc0, wc1, wc2, wc3;          // watch row for t
    float4 wn0, wn1, wn2, wn3;          // watch row for t+1
    {
        const float4* p0 = (const float4*)(combined + rowoff);
        wc0 = p0[0]; wc1 = p0[1]; wc2 = p0[2]; wc3 = p0[3];
        const float4* p1 = (const float4*)(combined + rowoff + stride);
        wn0 = p1[0]; wn1 = p1[1]; wn2 = p1[2]; wn3 = p1[3];
    }

    float P = 0.f, mp = 0.f, ip = 0.f, w0f = 0.f;
    float sv_store = 0.f;               // sus entering current t

    for (int t = 0; t < NCH; ++t) {
        combined[rowoff + 16 + c] = sv_store;   // fire-and-forget

        // prefetch watch row for t+2
        float4 wp0, wp1, wp2, wp3;
        if (t + 2 < NCH) {
            const float4* p2 = (const float4*)(combined + rowoff + 2 * stride);
            wp0 = p2[0]; wp1 = p2[1]; wp2 = p2[2]; wp3 = p2[3];
        } else {
            wp0 = wp1 = wp2 = wp3 = make_float4(0.f, 0.f, 0.f, 0.f);
        }

        // h = bs + sus-part (LN-folded) + watch-part
        float h0 = fmaf(ip, P - mp * u, bsc + w0f);
        float h1 = 0.f, h2 = 0.f, h3 = 0.f;
        h0 = fmaf(wc0.x, Wsw[0],  h0); h1 = fmaf(wc0.y, Wsw[1],  h1);
        h2 = fmaf(wc0.z, Wsw[2],  h2); h3 = fmaf(wc0.w, Wsw[3],  h3);
        h0 = fmaf(wc1.x, Wsw[4],  h0); h1 = fmaf(wc1.y, Wsw[5],  h1);
        h2 = fmaf(wc1.z, Wsw[6],  h2); h3 = fmaf(wc1.w, Wsw[7],  h3);
        h0 = fmaf(wc2.x, Wsw[8],  h0); h1 = fmaf(wc2.y, Wsw[9],  h1);
        h2 = fmaf(wc2.z, Wsw[10], h2); h3 = fmaf(wc2.w, Wsw[11], h3);
        h0 = fmaf(wc3.x, Wsw[12], h0); h1 = fmaf(wc3.y, Wsw[13], h1);
        h2 = fmaf(wc3.z, Wsw[14], h2); h3 = fmaf(wc3.w, Wsw[15], h3);
        float h = (h0 + h1) + (h2 + h3);

        // exact gelu
        float G = 0.5f * h * (1.f + erff(h * 0.70710678118654752f));

        // LDS round-trip for P (critical path)
        s_G[c] = G;
        const float4* gp = (const float4*)s_G;
        float4 xr[16];
        #pragma unroll
        for (int j4 = 0; j4 < 16; ++j4) xr[j4] = gp[j4];

        // (m, inv) reduce — pure VALU, runs parallel to the LDS reads
        float s1 = wave64_sum(G);
        float s2 = wave64_sum(G * G);
        float m   = s1 * (1.f / 64.f);
        float var = s2 * (1.f / 64.f) - m * m;
        float inv = rsqrtf(var + LNEPS);

        // P = sum_j G_j * Wsp_j   (8 accumulators)
        float p0=0.f,p1=0.f,p2=0.f,p3=0.f,p4=0.f,p5=0.f,p6=0.f,p7=0.f;
        #pragma unroll
        for (int j4 = 0; j4 < 16; j4 += 2) {
            float4 x0 = xr[j4], x1 = xr[j4 + 1];
            p0 = fmaf(x0.x, Wsp[4*j4+0], p0);
            p1 = fmaf(x0.y, Wsp[4*j4+1], p1);
            p2 = fmaf(x0.z, Wsp[4*j4+2], p2);
            p3 = fmaf(x0.w, Wsp[4*j4+3], p3);
            p4 = fmaf(x1.x, Wsp[4*j4+4], p4);
            p5 = fmaf(x1.y, Wsp[4*j4+5], p5);
            p6 = fmaf(x1.z, Wsp[4*j4+6], p6);
            p7 = fmaf(x1.w, Wsp[4*j4+7], p7);
        }
        P = ((p0 + p1) + (p2 + p3)) + ((p4 + p5) + (p6 + p7));

        // state for next iteration
        sv_store = fmaf((G - m) * inv, gd_c, bd_c);
        mp = m; ip = inv; w0f = w0;
        wc0 = wn0; wc1 = wn1; wc2 = wn2; wc3 = wn3;
        wn0 = wp0; wn1 = wp1; wn2 = wp2; wn3 = wp3;
        rowoff += stride;
    }
}

// ---------------------------------------------------------------------------
// Kernel 3 (v2): out = LN(combined @ Wd + bd) * g_check + b_check
// Split-bf16 MFMA GEMM: A = hi+lo, W = hi+lo; D ≈ hi·hi + lo·hi + hi·lo.
// Block = 32 rows (2 MFMA M-tiles) x 512 cols; 4 waves, each wave covers a
// 128-col slice (8 N-tiles) for both M-tiles. K padded 80->96 (3 k-steps).
// ---------------------------------------------------------------------------
#define M_BLK 32
__global__ __launch_bounds__(256) void out_mfma_kernel(
    const float* __restrict__ combined,
    const unsigned short* __restrict__ Bhi,
    const unsigned short* __restrict__ Blo,
    const float* __restrict__ bd, const float* __restrict__ g_check,
    const float* __restrict__ b_check, float* __restrict__ out)
{
    __shared__ __align__(16) unsigned short Ahi[M_BLK][104];  // pad 96->104
    __shared__ __align__(16) unsigned short Alo[M_BLK][104];
    __shared__ float red[4][M_BLK][2];

    const int tid = threadIdx.x;
    const size_t rowbase = (size_t)blockIdx.x * M_BLK;

    // stage + split-convert A (32 rows x 80), zero-pad k in [80,96)
    {
        const float4* src4 = (const float4*)(combined + rowbase * KDIM);
        #pragma unroll
        for (int u2 = 0; u2 < 3; ++u2) {
            int idx = tid + 256 * u2;
            if (idx < M_BLK * 20) {
                float4 v = src4[idx];
                int rr = idx / 20, k4 = idx % 20;
                float vs[4] = {v.x, v.y, v.z, v.w};
                #pragma unroll
                for (int e = 0; e < 4; ++e) {
                    unsigned short h = f2bf(vs[e]);
                    Ahi[rr][k4 * 4 + e] = h;
                    Alo[rr][k4 * 4 + e] = f2bf(vs[e] - bf2f(h));
                }
            }
        }
        #pragma unroll
        for (int u2 = 0; u2 < 2; ++u2) {
            int idx = tid + 256 * u2;            // 0..511 -> 32 rows x 16 ks
            int rr = idx >> 4, kk = 80 + (idx & 15);
            Ahi[rr][kk] = 0;
            Alo[rr][kk] = 0;
        }
    }

    const int lane  = tid & 63;
    const int wid   = tid >> 6;
    const int arowb = lane & 15;     // A row within M-tile / B col within N-tile
    const int kg    = lane >> 4;     // k-group (8 consecutive k each)

    // per-lane column metadata for this wave's 8 N-tiles
    int cols[8]; float bdv[8], gcv[8], bcv[8];
    #pragma unroll
    for (int n = 0; n < 8; ++n) {
        cols[n] = wid * 128 + n * 16 + arowb;
        bdv[n] = bd[cols[n]];
        gcv[n] = g_check[cols[n]];
        bcv[n] = b_check[cols[n]];
    }

    __syncthreads();

    // A fragments: row = lane&15, k = kg*8 + e  (+ 32*s)
    bf16x8 a_hi[2][3], a_lo[2][3];
    #pragma unroll
    for (int ms = 0; ms < 2; ++ms)
        #pragma unroll
        for (int s = 0; s < 3; ++s) {
            a_hi[ms][s] = *(const bf16x8*)&Ahi[ms * 16 + arowb][s * 32 + kg * 8];
            a_lo[ms][s] = *(const bf16x8*)&Alo[ms * 16 + arowb][s * 32 + kg * 8];
        }

    f32x4 acc[2][8];
    #pragma unroll
    for (int ms = 0; ms < 2; ++ms)
        #pragma unroll
        for (int n = 0; n < 8; ++n) acc[ms][n] = (f32x4){0.f, 0.f, 0.f, 0.f};

    #pragma unroll
    for (int n = 0; n < 8; ++n) {
        #pragma unroll
        for (int s = 0; s < 3; ++s) {
            size_t off = (((size_t)(s * 512 + cols[n])) * 4 + kg) * 8;
            bf16x8 bh = *(const bf16x8*)(Bhi + off);
            bf16x8 bl = *(const bf16x8*)(Blo + off);
            acc[0][n] = __builtin_amdgcn_mfma_f32_16x16x32_bf16(a_hi[0][s], bh, acc[0][n], 0, 0, 0);
            acc[1][n] = __builtin_amdgcn_mfma_f32_16x16x32_bf16(a_hi[1][s], bh, acc[1][n], 0, 0, 0);
            acc[0][n] = __builtin_amdgcn_mfma_f32_16x16x32_bf16(a_lo[0][s], bh, acc[0][n], 0, 0, 0);
            acc[1][n] = __builtin_amdgcn_mfma_f32_16x16x32_bf16(a_lo[1][s], bh, acc[1][n], 0, 0, 0);
            acc[0][n] = __builtin_amdgcn_mfma_f32_16x16x32_bf16(a_hi[0][s], bl, acc[0][n], 0, 0, 0);
            acc[1][n] = __builtin_amdgcn_mfma_f32_16x16x32_bf16(a_hi[1][s], bl, acc[1][n], 0, 0, 0);
        }
    }

    // bias + per-row LN partials over this wave's 128 cols.
    // D layout: row = kg*4 + j, col = lane&15 (+16n) -> row16 DPP reduce is
    // exactly "across the 16 lanes sharing kg".
    #pragma unroll
    for (int ms = 0; ms < 2; ++ms) {
        float s1[4] = {0.f, 0.f, 0.f, 0.f};
        float s2[4] = {0.f, 0.f, 0.f, 0.f};
        #pragma unroll
        for (int n = 0; n < 8; ++n) {
            #pragma unroll
            for (int j = 0; j < 4; ++j) {
                float v = acc[ms][n][j] + bdv[n];
                acc[ms][n][j] = v;
                s1[j] += v;
                s2[j] = fmaf(v, v, s2[j]);
            }
        }
        #pragma unroll
        for (int j = 0; j < 4; ++j) {
            s1[j] = row16_sum(s1[j]);
            s2[j] = row16_sum(s2[j]);
        }
        if (arowb == 0) {
            #pragma unroll
            for (int j = 0; j < 4; ++j) {
                red[wid][ms * 16 + kg * 4 + j][0] = s1[j];
                red[wid][ms * 16 + kg * 4 + j][1] = s2[j];
            }
        }
    }
    __syncthreads();

    #pragma unroll
    for (int ms = 0; ms < 2; ++ms) {
        #pragma unroll
        for (int j = 0; j < 4; ++j) {
            const int rowl = ms * 16 + kg * 4 + j;
            float t1 = (red[0][rowl][0] + red[1][rowl][0])
                     + (red[2][rowl][0] + red[3][rowl][0]);
            float t2 = (red[0][rowl][1] + red[1][rowl][1])
                     + (red[2][rowl][1] + red[3][rowl][1]);
            float mm  = t1 * (1.f / 512.f);
            float var = t2 * (1.f / 512.f) - mm * mm;
            float iv  = rsqrtf(var + LNEPS);

            size_t R = rowbase + (size_t)rowl;
            int ii  = (int)(R & 15);
            int bb2 = (int)((R >> 4) & 31);
            int tt  = (int)(R >> 9);
            size_t orow = ((size_t)bb2 * SS + (size_t)tt * CURD + ii) * OUTD;

            #pragma unroll
            for (int n = 0; n < 8; ++n) {
                out[orow + cols[n]] =
                    (acc[ms][n][j] - mm) * iv * gcv[n] + bcv[n];
            }
        }
    }
}

// ---------------------------------------------------------------------------
extern "C" void kernel_launch(void* const* d_in, const int* in_sizes, int n_in,
                              void* d_out, int out_size, void* d_ws, size_t ws_size,
                              hipStream_t stream)
{
    const int*   x       = (const int*)  d_in[0];
    const float* emb     = (const float*)d_in[1];
    const float* Wq      = (const float*)d_in[2];
    const float* bq      = (const float*)d_in[3];
    const float* Wk      = (const float*)d_in[4];
    const float* bk      = (const float*)d_in[5];
    const float* Wv      = (const float*)d_in[6];
    const float* bv      = (const float*)d_in[7];
    const float* g_lim   = (const float*)d_in[8];
    const float* b_lim   = (const float*)d_in[9];
    const float* Ws      = (const float*)d_in[10];
    const float* bs      = (const float*)d_in[11];
    const float* g_doubt = (const float*)d_in[12];
    const float* b_doubt = (const float*)d_in[13];
    const float* Wd      = (const float*)d_in[14];
    const float* bd      = (const float*)d_in[15];
    const float* g_check = (const float*)d_in[16];
    const float* b_check = (const float*)d_in[17];

    float* out      = (float*)d_out;
    float* combined = (float*)d_ws;    // [NCH][BB][CURD][KDIM] fp32 = 40 MB
    // packed Wd (bf16 hi/lo, 96x512 each) just past combined
    unsigned short* whi = (unsigned short*)((char*)d_ws + 41943040);
    unsigned short* wlo = whi + 96 * 512;

    wd_pack_kernel<<<dim3(192), dim3(256), 0, stream>>>(Wd, whi, wlo);

    attn_kernel<<<dim3(NCH * BB / 4), dim3(256), 0, stream>>>(
        x, emb, Wq, bq, Wk, bk, Wv, bv, g_lim, b_lim, combined);

    rec_kernel<<<dim3(BB * CURD), dim3(64), 0, stream>>>(
        Ws, bs, g_doubt, b_doubt, combined);

    out_mfma_kernel<<<dim3((NCH * BB * CURD) / M_BLK), dim3(256), 0, stream>>>(
        combined, whi, wlo, bd, g_check, b_check, out);
}